// Round 14
// baseline (1301.348 us; speedup 1.0000x reference)
//
#include <hip/hip_runtime.h>
#include <cstdint>
#include <cstddef>

#define N_TOK 65536
#define DIM 512
#define FF 2048
#define NE 8
#define HCAP 24576           // per-expert row capacity covered by tile enumeration
#define MAXT 1032            // tight bound: sum_e ceil(count_e/128) <= 1031

typedef __attribute__((ext_vector_type(8))) short short8;
typedef __attribute__((ext_vector_type(4))) float f32x4;

__device__ __forceinline__ unsigned f2bf(float f) {
  unsigned u = __builtin_bit_cast(unsigned, f);
  u = u + 0x7fffu + ((u >> 16) & 1u);
  return (u >> 16) & 0xffffu;
}

__device__ __forceinline__ void gload_lds16(const void* g, void* l) {
  __builtin_amdgcn_global_load_lds((const __attribute__((address_space(1))) void*)g,
                                   (__attribute__((address_space(3))) void*)l, 16, 0, 0);
}

// ---------------- transpose + cast: in (rows x cols) f32 -> out (cols x rows) bf16, per expert
__global__ __launch_bounds__(256) void k_transpose_cast(
    const float* __restrict__ in, unsigned short* __restrict__ outp, int rows, int cols)
{
  __shared__ float tile[32][33];
  const float* ine = in + (size_t)blockIdx.z * rows * cols;
  unsigned short* oute = outp + (size_t)blockIdx.z * rows * cols;
  int tx = threadIdx.x & 31, ty = threadIdx.x >> 5;
  int r0 = blockIdx.y * 32, c0 = blockIdx.x * 32;
#pragma unroll
  for (int i = 0; i < 4; ++i)
    tile[ty + i*8][tx] = ine[(size_t)(r0 + ty + i*8)*cols + c0 + tx];
  __syncthreads();
#pragma unroll
  for (int i = 0; i < 4; ++i) {
    int r = c0 + ty + i*8, c = r0 + tx;
    oute[(size_t)r*rows + c] = (unsigned short)f2bf(tile[tx][ty + i*8]);
  }
}

// ---------------- router: logits, top-2, weight, counts; also casts x -> xb (bf16)
__global__ __launch_bounds__(256) void k_router(
    const float* __restrict__ x, const float* __restrict__ Wr,
    unsigned short* __restrict__ xb, int2* __restrict__ tinfo, int* __restrict__ cnt)
{
  __shared__ int lcnt[8];
  int tid = threadIdx.x, lane = tid & 63, wv = tid >> 6;
  if (tid < 8) lcnt[tid] = 0;
  float wr[8][8];
#pragma unroll
  for (int j = 0; j < 8; ++j) {
    const float4* p = (const float4*)(Wr + (size_t)(lane*8 + j)*NE);
    float4 a = p[0], b = p[1];
    wr[j][0]=a.x; wr[j][1]=a.y; wr[j][2]=a.z; wr[j][3]=a.w;
    wr[j][4]=b.x; wr[j][5]=b.y; wr[j][6]=b.z; wr[j][7]=b.w;
  }
  __syncthreads();
  int t0 = blockIdx.x*64 + wv*16;
  for (int it = 0; it < 16; ++it) {
    int t = t0 + it;
    const float4* xp = (const float4*)(x + (size_t)t*DIM + lane*8);
    float4 v0 = xp[0], v1 = xp[1];
    float xv[8] = {v0.x,v0.y,v0.z,v0.w,v1.x,v1.y,v1.z,v1.w};
    uint4 pk;
    pk.x = f2bf(xv[0]) | (f2bf(xv[1]) << 16);
    pk.y = f2bf(xv[2]) | (f2bf(xv[3]) << 16);
    pk.z = f2bf(xv[4]) | (f2bf(xv[5]) << 16);
    pk.w = f2bf(xv[6]) | (f2bf(xv[7]) << 16);
    *(uint4*)(xb + (size_t)t*DIM + lane*8) = pk;
    float lg[8];
#pragma unroll
    for (int e2 = 0; e2 < 8; ++e2) lg[e2] = 0.f;
#pragma unroll
    for (int j = 0; j < 8; ++j)
#pragma unroll
      for (int e2 = 0; e2 < 8; ++e2) lg[e2] += xv[j]*wr[j][e2];
#pragma unroll
    for (int off = 32; off >= 1; off >>= 1)
#pragma unroll
      for (int e2 = 0; e2 < 8; ++e2) lg[e2] += __shfl_xor(lg[e2], off, 64);
    int e0 = 0; float v0m = lg[0];
#pragma unroll
    for (int e2 = 1; e2 < 8; ++e2) if (lg[e2] > v0m) { v0m = lg[e2]; e0 = e2; }
    int e1 = -1; float v1m = -3.0e38f;
#pragma unroll
    for (int e2 = 0; e2 < 8; ++e2) if (e2 != e0 && lg[e2] > v1m) { v1m = lg[e2]; e1 = e2; }
    float w0 = 1.f / (1.f + __expf((v1m - v0m) * 0.4f));   // 1/T = 1/2.5
    if (lane == 0) {
      atomicAdd(&lcnt[e0], 1);
      atomicAdd(&lcnt[e1], 1);
      tinfo[t] = make_int2(e0 | (e1 << 8), __float_as_int(w0));
    }
  }
  __syncthreads();
  if (tid < 8) atomicAdd(&cnt[tid*16], lcnt[tid]);
}

// ---------------- pass 2: scan counts -> row bases, tile bases, total tiles; zero cursors
__global__ void k_offsets(int* cnt) {
  if (threadIdx.x == 0) {
    int base = 0, tb = 0;
    for (int e2 = 0; e2 < 8; ++e2) {
      int c = cnt[e2*16]; if (c > HCAP) c = HCAP;
      cnt[e2*16 + 1] = base;          // row base (gbase)
      base += cnt[e2*16];
      cnt[e2*16 + 2] = 0;             // fill cursor
      cnt[e2*16 + 3] = tb;            // tile base
      tb += (c + 127) >> 7;
    }
    cnt[135] = tb;                    // total tiles
  }
}

// ---------------- pass 3: slot assignment only (token list + weights; no x copy)
__global__ __launch_bounds__(128) void k_fill(
    const int2* __restrict__ tinfo, int* __restrict__ tokl,
    float* __restrict__ pwl, int* __restrict__ cnt)
{
  __shared__ int lc[8], lbase[8], gb[8];
  __shared__ unsigned char ce[128];
  __shared__ int csl[128];
  __shared__ float cw[128];
  int tid = threadIdx.x;
  if (tid < 8) { lc[tid] = 0; gb[tid] = cnt[tid*16 + 1]; }
  __syncthreads();
  if (tid < 64) {
    int t = blockIdx.x*64 + tid;
    int2 inf = tinfo[t];
    int e0 = inf.x & 0xff, e1 = (inf.x >> 8) & 0xff;
    float w0 = __int_as_float(inf.y);
    int i0 = tid*2, i1 = i0 + 1;
    ce[i0] = (unsigned char)e0; cw[i0] = w0;        csl[i0] = atomicAdd(&lc[e0], 1);
    ce[i1] = (unsigned char)e1; cw[i1] = 1.f - w0;  csl[i1] = atomicAdd(&lc[e1], 1);
  }
  __syncthreads();
  if (tid < 8) lbase[tid] = atomicAdd(&cnt[tid*16 + 2], lc[tid]);
  __syncthreads();
  int e = ce[tid];
  int p = gb[e] + lbase[e] + csl[tid];
  tokl[p] = blockIdx.x*64 + (tid >> 1);
  pwl[p]  = cw[tid];
}

// ================= 128x128 GEMM core pieces (r12 double-buffered structure) =================
__device__ __forceinline__ void stage128(
    const unsigned short* __restrict__ src, size_t stride, int k0,
    unsigned short* __restrict__ buf, int tid)
{
#pragma unroll
  for (int j = 0; j < 4; ++j) {
    int lrow = j*32 + (tid >> 3);
    gload_lds16(src + (size_t)lrow*stride + k0 + (((tid & 7) ^ (lrow & 7)) << 3),
                buf + j*2048 + tid*8);
  }
}

__device__ __forceinline__ int tile_expert(const int* cnt, int gt) {
  int e = 0;
#pragma unroll
  for (int k = 1; k < 8; ++k) if (gt >= cnt[k*16 + 3]) e = k;
  return e;
}

__device__ __forceinline__ void mfma_step(
    const unsigned short* __restrict__ ab, const unsigned short* __restrict__ bb,
    f32x4 acc[4][4], int r16, int g4, int wm, int wn)
{
  short8 af[4][2], bf[4][2];
#pragma unroll
  for (int mf = 0; mf < 4; ++mf) {
    int row = wm*64 + mf*16 + r16;
#pragma unroll
    for (int k2 = 0; k2 < 2; ++k2)
      af[mf][k2] = *(const short8*)(ab + row*64 + ((((k2 << 2) + g4) ^ (row & 7)) << 3));
  }
#pragma unroll
  for (int nf = 0; nf < 4; ++nf) {
    int row = wn*64 + nf*16 + r16;
#pragma unroll
    for (int k2 = 0; k2 < 2; ++k2)
      bf[nf][k2] = *(const short8*)(bb + row*64 + ((((k2 << 2) + g4) ^ (row & 7)) << 3));
  }
  __builtin_amdgcn_s_setprio(1);
#pragma unroll
  for (int k2 = 0; k2 < 2; ++k2)
#pragma unroll
    for (int mf = 0; mf < 4; ++mf)
#pragma unroll
      for (int nf = 0; nf < 4; ++nf)
        acc[mf][nf] = __builtin_amdgcn_mfma_f32_16x16x32_bf16(
            af[mf][k2], bf[nf][k2], acc[mf][nf], 0, 0, 0);
  __builtin_amdgcn_s_setprio(0);
}

// ---------------- K1 (chunked): h_local[lt] = gelu(gather(xb) @ W1^T + b1)
// bid decode: n = (bid&7)|(((bid>>3)&1)<<3), lt = bid>>4  -> XCD = n%8 (W1 panels L2-resident).
__global__ __launch_bounds__(256, 2) void k_gemm1(
    const unsigned short* __restrict__ xb, const unsigned short* __restrict__ w1t,
    const float* __restrict__ b1, const int* __restrict__ cnt,
    const int* __restrict__ tokl, unsigned short* __restrict__ h, int T0, int cap)
{
  const int bid = blockIdx.x;
  const int n  = (bid & 7) | (((bid >> 3) & 1) << 3);
  const int lt = bid >> 4;
  const int gt = T0 + lt;
  if (lt >= cap || gt >= cnt[135]) return;
  const int e = tile_expert(cnt, gt);
  const int m = gt - cnt[e*16 + 3];
  const int count0 = cnt[e*16];
  const int count = count0 < HCAP ? count0 : HCAP;
  const int row0 = m*128;
  const int gbase = cnt[e*16 + 1];

  __shared__ __align__(16) unsigned short lds[32768];   // 64 KB
  unsigned short* As = lds;
  unsigned short* Bs = lds + 16384;

  const int tid = threadIdx.x, lane = tid & 63, wv = tid >> 6;
  const int r16 = lane & 15, g4 = lane >> 4;
  const int wm = wv >> 1, wn = wv & 1;

  int rows4[4];
#pragma unroll
  for (int j = 0; j < 4; ++j) {
    int rr = row0 + j*32 + (tid >> 3);
    if (rr > count - 1) rr = count - 1;
    rows4[j] = tokl[gbase + rr];
  }
  const int axor = ((tid & 7) ^ ((tid >> 3) & 7)) << 3;
  const unsigned short* w1p = w1t + (size_t)e*FF*DIM + (size_t)(n*128)*DIM;

  auto stageA = [&](unsigned short* buf, int k0) {
#pragma unroll
    for (int j = 0; j < 4; ++j)
      gload_lds16(xb + (size_t)rows4[j]*DIM + k0 + axor, buf + j*2048 + tid*8);
  };

  const f32x4 fz = {0.f, 0.f, 0.f, 0.f};
  f32x4 acc[4][4];
#pragma unroll
  for (int a = 0; a < 4; ++a)
#pragma unroll
    for (int b = 0; b < 4; ++b) acc[a][b] = fz;

  stageA(As, 0);
  stage128(w1p, DIM, 0, Bs, tid);
  __syncthreads();
  int buf = 0;
  for (int kk = 0; kk < DIM/64; ++kk) {
    if (kk + 1 < DIM/64) {
      stageA(As + (buf ^ 1)*8192, (kk + 1)*64);
      stage128(w1p, DIM, (kk + 1)*64, Bs + (buf ^ 1)*8192, tid);
    }
    mfma_step(As + buf*8192, Bs + buf*8192, acc, r16, g4, wm, wn);
    __syncthreads();
    buf ^= 1;
  }

  float b1v[4];
#pragma unroll
  for (int nf = 0; nf < 4; ++nf)
    b1v[nf] = b1[(size_t)e*FF + n*128 + wn*64 + nf*16 + r16];

  unsigned short* hs = lds;       // [128][136] overlay (all GEMM reads complete)
#pragma unroll
  for (int mf = 0; mf < 4; ++mf)
#pragma unroll
    for (int nf = 0; nf < 4; ++nf) {
      int col = wn*64 + nf*16 + r16;
#pragma unroll
      for (int i = 0; i < 4; ++i) {
        int row = wm*64 + mf*16 + g4*4 + i;
        float v = acc[mf][nf][i] + b1v[nf];
        float u = v * (0.7978845608028654f + 0.0356774081f*v*v);
        float gl = v * __builtin_amdgcn_rcpf(1.f + __expf(-2.f*u));  // v*sigmoid(2u)
        hs[row*136 + col] = (unsigned short)f2bf(gl);
      }
    }
  __syncthreads();
  unsigned short* hdst = h + (size_t)lt*(128*FF);
#pragma unroll
  for (int j = 0; j < 8; ++j) {
    int o = j*256 + tid;
    int row = o >> 4, part = o & 15;
    if (row0 + row < count)
      *(uint4*)(hdst + (size_t)row*FF + n*128 + part*8) =
          *(const uint4*)(hs + row*136 + part*8);
  }
}

// ---------------- K2 (chunked, split-K=2): out += w * (h_local[lt] @ W2^T [+ b2 if ks==0])
// bid decode: lt = (bid>>6)*8 + (bid&7); inner = (bid>>3)&7; n = inner&3; ks = inner>>2.
// XCD = bid%8 = lt%8: all 8 (n,ks) blocks of a tile on one XCD (W2 + A-halves local).
// Split-K partials merge via the existing f32 atomicAdd (commutative, same semantics).
__global__ __launch_bounds__(256, 2) void k_gemm2(
    const unsigned short* __restrict__ h, const unsigned short* __restrict__ w2t,
    const float* __restrict__ b2, const int* __restrict__ tokl,
    const float* __restrict__ pwl, const int* __restrict__ cnt,
    float* __restrict__ out, int T0, int cap)
{
  const int bid = blockIdx.x;
  const int lt = (bid >> 6)*8 + (bid & 7);
  const int inner = (bid >> 3) & 7;
  const int n  = inner & 3;
  const int ks = inner >> 2;
  const int gt = T0 + lt;
  if (lt >= cap || gt >= cnt[135]) return;
  const int e = tile_expert(cnt, gt);
  const int m = gt - cnt[e*16 + 3];
  const int count0 = cnt[e*16];
  const int count = count0 < HCAP ? count0 : HCAP;
  const int row0 = m*128;
  const int gbase = cnt[e*16 + 1];

  __shared__ __align__(16) unsigned short lds[32768];   // 64 KB
  unsigned short* As = lds;
  unsigned short* Bs = lds + 16384;

  const int tid = threadIdx.x, lane = tid & 63, wv = tid >> 6;
  const int r16 = lane & 15, g4 = lane >> 4;
  const int wm = wv >> 1, wn = wv & 1;

  const int kbase = ks * (FF/2);                 // element offset of this K-half
  const unsigned short* ap = h + (size_t)lt*(128*FF);
  const unsigned short* bp = w2t + (size_t)e*DIM*FF + (size_t)(n*128)*FF;

  const f32x4 fz = {0.f, 0.f, 0.f, 0.f};
  f32x4 acc[4][4];
#pragma unroll
  for (int a = 0; a < 4; ++a)
#pragma unroll
    for (int b = 0; b < 4; ++b) acc[a][b] = fz;

  stage128(ap, FF, kbase, As, tid);
  stage128(bp, FF, kbase, Bs, tid);
  __syncthreads();
  int buf = 0;
  const int NK = FF/128;                         // 16 k-steps per half
  for (int kk = 0; kk < NK; ++kk) {
    if (kk + 1 < NK) {
      stage128(ap, FF, kbase + (kk + 1)*64, As + (buf ^ 1)*8192, tid);
      stage128(bp, FF, kbase + (kk + 1)*64, Bs + (buf ^ 1)*8192, tid);
    }
    mfma_step(As + buf*8192, Bs + buf*8192, acc, r16, g4, wm, wn);
    __syncthreads();
    buf ^= 1;
  }

  float b2v[4];
#pragma unroll
  for (int nf = 0; nf < 4; ++nf)
    b2v[nf] = (ks == 0) ? b2[(size_t)e*DIM + n*128 + wn*64 + nf*16 + r16] : 0.f;

#pragma unroll
  for (int mf = 0; mf < 4; ++mf)
#pragma unroll
    for (int i = 0; i < 4; ++i) {
      int lrow = row0 + wm*64 + mf*16 + g4*4 + i;
      if (lrow < count) {
        int tk = tokl[gbase + lrow];
        float wg = pwl[gbase + lrow];
#pragma unroll
        for (int nf = 0; nf < 4; ++nf) {
          int d = n*128 + wn*64 + nf*16 + r16;
          atomicAdd(out + (size_t)tk*DIM + d, (acc[mf][nf][i] + b2v[nf]) * wg);
        }
      }
    }
}

extern "C" void kernel_launch(void* const* d_in, const int* in_sizes, int n_in,
                              void* d_out, int out_size, void* d_ws, size_t ws_size,
                              hipStream_t stream)
{
  const float* x  = (const float*)d_in[0];
  const float* Wr = (const float*)d_in[1];
  const float* W1 = (const float*)d_in[2];
  const float* b1 = (const float*)d_in[3];
  const float* W2 = (const float*)d_in[4];
  const float* b2 = (const float*)d_in[5];
  float* out = (float*)d_out;
  (void)in_sizes; (void)n_in;

  char* ws = (char*)d_ws;
  unsigned short* xb  = (unsigned short*)(ws);                    // 64 MB bf16 x (ungathered)
  unsigned short* w1t = (unsigned short*)(ws + 67108864);         // 16 MB W1^T bf16
  unsigned short* w2t = (unsigned short*)(ws + 83886080);         // 16 MB W2^T bf16
  int2*  tinfo = (int2*)(ws + 100663296);                         // 512 KB per-token routing
  int*   tokl  = (int*)(ws + 101187584);                          // 512 KB token list (gathered order)
  float* pwl   = (float*)(ws + 101711872);                        // 512 KB pair weights
  int*   cnt   = (int*)(ws + 102236160);                          // 1 KB counts/bases/tiles
  unsigned short* h = (unsigned short*)(ws + 102237184);          // chunk h, cap tiles

  const size_t FIXED = 102237184ULL;
  const size_t TILEB = (size_t)128 * FF * 2;
  long cap_l = (ws_size > FIXED) ? (long)((ws_size - FIXED) / TILEB) : 0;
  int cap = (int)(cap_l < MAXT ? cap_l : MAXT);
  if (cap > 256) cap = 256;     // keep h-chunk <= 134 MB
  if (cap < 8)  cap = 8;        // safety floor (ws >= 270 MB proven in r7)
  const int nch = (MAXT + cap - 1) / cap;
  const int ngrp = (cap + 7) / 8;

  hipMemsetAsync(cnt, 0, 256*sizeof(int), stream);
  hipMemsetAsync(d_out, 0, (size_t)out_size*sizeof(float), stream);

  dim3 g1(FF/32, DIM/32, NE);
  k_transpose_cast<<<g1, 256, 0, stream>>>(W1, w1t, DIM, FF);
  dim3 g2(DIM/32, FF/32, NE);
  k_transpose_cast<<<g2, 256, 0, stream>>>(W2, w2t, FF, DIM);

  k_router<<<N_TOK/64, 256, 0, stream>>>(x, Wr, xb, tinfo, cnt);
  k_offsets<<<1, 64, 0, stream>>>(cnt);
  k_fill<<<N_TOK/64, 128, 0, stream>>>(tinfo, tokl, pwl, cnt);

  for (int c = 0; c < nch; ++c) {
    const int T0 = c * cap;
    k_gemm1<<<ngrp*128, 256, 0, stream>>>(xb, w1t, b1, cnt, tokl, h, T0, cap);
    k_gemm2<<<ngrp*64,  256, 0, stream>>>(h, w2t, b2, tokl, pwl, cnt, out, T0, cap);
  }
}

// Round 15
// 1088.319 us; speedup vs baseline: 1.1957x; 1.1957x over previous
//
#include <hip/hip_runtime.h>
#include <cstdint>
#include <cstddef>

#define N_TOK 65536
#define DIM 512
#define FF 2048
#define NE 8
#define HCAP 24576           // per-expert row capacity covered by tile enumeration
#define MAXT 1032            // tight bound: sum_e ceil(count_e/128) <= 1031

typedef __attribute__((ext_vector_type(8))) short short8;
typedef __attribute__((ext_vector_type(4))) float f32x4;

__device__ __forceinline__ unsigned f2bf(float f) {
  unsigned u = __builtin_bit_cast(unsigned, f);
  u = u + 0x7fffu + ((u >> 16) & 1u);
  return (u >> 16) & 0xffffu;
}

__device__ __forceinline__ void gload_lds16(const void* g, void* l) {
  __builtin_amdgcn_global_load_lds((const __attribute__((address_space(1))) void*)g,
                                   (__attribute__((address_space(3))) void*)l, 16, 0, 0);
}

// ---------------- transpose + cast: in (rows x cols) f32 -> out (cols x rows) bf16, per expert
__global__ __launch_bounds__(256) void k_transpose_cast(
    const float* __restrict__ in, unsigned short* __restrict__ outp, int rows, int cols)
{
  __shared__ float tile[32][33];
  const float* ine = in + (size_t)blockIdx.z * rows * cols;
  unsigned short* oute = outp + (size_t)blockIdx.z * rows * cols;
  int tx = threadIdx.x & 31, ty = threadIdx.x >> 5;
  int r0 = blockIdx.y * 32, c0 = blockIdx.x * 32;
#pragma unroll
  for (int i = 0; i < 4; ++i)
    tile[ty + i*8][tx] = ine[(size_t)(r0 + ty + i*8)*cols + c0 + tx];
  __syncthreads();
#pragma unroll
  for (int i = 0; i < 4; ++i) {
    int r = c0 + ty + i*8, c = r0 + tx;
    oute[(size_t)r*rows + c] = (unsigned short)f2bf(tile[tx][ty + i*8]);
  }
}

// ---------------- router: logits, top-2, weight, counts; also casts x -> xb (bf16)
__global__ __launch_bounds__(256) void k_router(
    const float* __restrict__ x, const float* __restrict__ Wr,
    unsigned short* __restrict__ xb, int2* __restrict__ tinfo, int* __restrict__ cnt)
{
  __shared__ int lcnt[8];
  int tid = threadIdx.x, lane = tid & 63, wv = tid >> 6;
  if (tid < 8) lcnt[tid] = 0;
  float wr[8][8];
#pragma unroll
  for (int j = 0; j < 8; ++j) {
    const float4* p = (const float4*)(Wr + (size_t)(lane*8 + j)*NE);
    float4 a = p[0], b = p[1];
    wr[j][0]=a.x; wr[j][1]=a.y; wr[j][2]=a.z; wr[j][3]=a.w;
    wr[j][4]=b.x; wr[j][5]=b.y; wr[j][6]=b.z; wr[j][7]=b.w;
  }
  __syncthreads();
  int t0 = blockIdx.x*64 + wv*16;
  for (int it = 0; it < 16; ++it) {
    int t = t0 + it;
    const float4* xp = (const float4*)(x + (size_t)t*DIM + lane*8);
    float4 v0 = xp[0], v1 = xp[1];
    float xv[8] = {v0.x,v0.y,v0.z,v0.w,v1.x,v1.y,v1.z,v1.w};
    uint4 pk;
    pk.x = f2bf(xv[0]) | (f2bf(xv[1]) << 16);
    pk.y = f2bf(xv[2]) | (f2bf(xv[3]) << 16);
    pk.z = f2bf(xv[4]) | (f2bf(xv[5]) << 16);
    pk.w = f2bf(xv[6]) | (f2bf(xv[7]) << 16);
    *(uint4*)(xb + (size_t)t*DIM + lane*8) = pk;
    float lg[8];
#pragma unroll
    for (int e2 = 0; e2 < 8; ++e2) lg[e2] = 0.f;
#pragma unroll
    for (int j = 0; j < 8; ++j)
#pragma unroll
      for (int e2 = 0; e2 < 8; ++e2) lg[e2] += xv[j]*wr[j][e2];
#pragma unroll
    for (int off = 32; off >= 1; off >>= 1)
#pragma unroll
      for (int e2 = 0; e2 < 8; ++e2) lg[e2] += __shfl_xor(lg[e2], off, 64);
    int e0 = 0; float v0m = lg[0];
#pragma unroll
    for (int e2 = 1; e2 < 8; ++e2) if (lg[e2] > v0m) { v0m = lg[e2]; e0 = e2; }
    int e1 = -1; float v1m = -3.0e38f;
#pragma unroll
    for (int e2 = 0; e2 < 8; ++e2) if (e2 != e0 && lg[e2] > v1m) { v1m = lg[e2]; e1 = e2; }
    float w0 = 1.f / (1.f + __expf((v1m - v0m) * 0.4f));   // 1/T = 1/2.5
    if (lane == 0) {
      atomicAdd(&lcnt[e0], 1);
      atomicAdd(&lcnt[e1], 1);
      tinfo[t] = make_int2(e0 | (e1 << 8), __float_as_int(w0));
    }
  }
  __syncthreads();
  if (tid < 8) atomicAdd(&cnt[tid*16], lcnt[tid]);
}

// ---------------- pass 2: scan counts -> row bases, tile bases, total tiles; zero cursors
__global__ void k_offsets(int* cnt) {
  if (threadIdx.x == 0) {
    int base = 0, tb = 0;
    for (int e2 = 0; e2 < 8; ++e2) {
      int c = cnt[e2*16]; if (c > HCAP) c = HCAP;
      cnt[e2*16 + 1] = base;          // row base (gbase)
      base += cnt[e2*16];
      cnt[e2*16 + 2] = 0;             // fill cursor
      cnt[e2*16 + 3] = tb;            // tile base
      tb += (c + 127) >> 7;
    }
    cnt[135] = tb;                    // total tiles
  }
}

// ---------------- pass 3: slot assignment only (token list + weights; no x copy)
__global__ __launch_bounds__(128) void k_fill(
    const int2* __restrict__ tinfo, int* __restrict__ tokl,
    float* __restrict__ pwl, int* __restrict__ cnt)
{
  __shared__ int lc[8], lbase[8], gb[8];
  __shared__ unsigned char ce[128];
  __shared__ int csl[128];
  __shared__ float cw[128];
  int tid = threadIdx.x;
  if (tid < 8) { lc[tid] = 0; gb[tid] = cnt[tid*16 + 1]; }
  __syncthreads();
  if (tid < 64) {
    int t = blockIdx.x*64 + tid;
    int2 inf = tinfo[t];
    int e0 = inf.x & 0xff, e1 = (inf.x >> 8) & 0xff;
    float w0 = __int_as_float(inf.y);
    int i0 = tid*2, i1 = i0 + 1;
    ce[i0] = (unsigned char)e0; cw[i0] = w0;        csl[i0] = atomicAdd(&lc[e0], 1);
    ce[i1] = (unsigned char)e1; cw[i1] = 1.f - w0;  csl[i1] = atomicAdd(&lc[e1], 1);
  }
  __syncthreads();
  if (tid < 8) lbase[tid] = atomicAdd(&cnt[tid*16 + 2], lc[tid]);
  __syncthreads();
  int e = ce[tid];
  int p = gb[e] + lbase[e] + csl[tid];
  tokl[p] = blockIdx.x*64 + (tid >> 1);
  pwl[p]  = cw[tid];
}

// ================= 128x128 GEMM pieces — BK=32 double-buffered, 4 blocks/CU =================
// A/B chunk = [128 rows][32 k] bf16 = 8 KB; 2 buffers each: K2 LDS = 32 KB, K1 = 34.8 KB
// (hs overlay) -> 4 blocks/CU (16 waves) for stall coverage; r12 prefetch schedule kept.
// Slot-XOR: 4 slots/row (64 B); LDS dest stays gload_lds-linear, source pre-swizzled ^(row&3).
__device__ __forceinline__ void stage32(
    const unsigned short* __restrict__ src, size_t stride, int k0,
    unsigned short* __restrict__ buf, int tid)
{
#pragma unroll
  for (int j = 0; j < 2; ++j) {
    int lrow = j*64 + (tid >> 2);
    gload_lds16(src + (size_t)lrow*stride + k0 + ((((tid & 3) ^ ((tid >> 2) & 3))) << 3),
                buf + j*2048 + tid*8);
  }
}

__device__ __forceinline__ int tile_expert(const int* cnt, int gt) {
  int e = 0;
#pragma unroll
  for (int k = 1; k < 8; ++k) if (gt >= cnt[k*16 + 3]) e = k;
  return e;
}

__device__ __forceinline__ void mfma_step32(
    const unsigned short* __restrict__ ab, const unsigned short* __restrict__ bb,
    f32x4 acc[4][4], int r16, int g4, int wm, int wn)
{
  short8 af[4], bf[4];
#pragma unroll
  for (int mf = 0; mf < 4; ++mf) {
    int row = wm*64 + mf*16 + r16;
    af[mf] = *(const short8*)(ab + row*32 + ((g4 ^ (row & 3)) << 3));
  }
#pragma unroll
  for (int nf = 0; nf < 4; ++nf) {
    int row = wn*64 + nf*16 + r16;
    bf[nf] = *(const short8*)(bb + row*32 + ((g4 ^ (row & 3)) << 3));
  }
  __builtin_amdgcn_s_setprio(1);
#pragma unroll
  for (int mf = 0; mf < 4; ++mf)
#pragma unroll
    for (int nf = 0; nf < 4; ++nf)
      acc[mf][nf] = __builtin_amdgcn_mfma_f32_16x16x32_bf16(
          af[mf], bf[nf], acc[mf][nf], 0, 0, 0);
  __builtin_amdgcn_s_setprio(0);
}

// ---------------- K1 (chunked): h_local[lt] = gelu(gather(xb) @ W1^T + b1)
// bid decode: n = (bid&7)|(((bid>>3)&1)<<3), lt = bid>>4  -> XCD = n%8 (W1 panels L2-resident).
__global__ __launch_bounds__(256, 4) void k_gemm1(
    const unsigned short* __restrict__ xb, const unsigned short* __restrict__ w1t,
    const float* __restrict__ b1, const int* __restrict__ cnt,
    const int* __restrict__ tokl, unsigned short* __restrict__ h, int T0, int cap)
{
  const int bid = blockIdx.x;
  const int n  = (bid & 7) | (((bid >> 3) & 1) << 3);
  const int lt = bid >> 4;
  const int gt = T0 + lt;
  if (lt >= cap || gt >= cnt[135]) return;
  const int e = tile_expert(cnt, gt);
  const int m = gt - cnt[e*16 + 3];
  const int count0 = cnt[e*16];
  const int count = count0 < HCAP ? count0 : HCAP;
  const int row0 = m*128;
  const int gbase = cnt[e*16 + 1];

  __shared__ __align__(16) unsigned short lds[17408];   // 34.8 KB (max of 32 KB bufs / hs)
  unsigned short* As = lds;          // 2 x 4096 shorts
  unsigned short* Bs = lds + 8192;   // 2 x 4096 shorts

  const int tid = threadIdx.x, lane = tid & 63, wv = tid >> 6;
  const int r16 = lane & 15, g4 = lane >> 4;
  const int wm = wv >> 1, wn = wv & 1;

  // gathered row bases: 2 per thread (rows tid>>2 and 64+(tid>>2)), clamped
  int rows2[2];
#pragma unroll
  for (int j = 0; j < 2; ++j) {
    int rr = row0 + j*64 + (tid >> 2);
    if (rr > count - 1) rr = count - 1;
    rows2[j] = tokl[gbase + rr];
  }
  const int axor = (((tid & 3) ^ ((tid >> 2) & 3))) << 3;
  const unsigned short* w1p = w1t + (size_t)e*FF*DIM + (size_t)(n*128)*DIM;

  auto stageA = [&](unsigned short* buf, int k0) {
#pragma unroll
    for (int j = 0; j < 2; ++j)
      gload_lds16(xb + (size_t)rows2[j]*DIM + k0 + axor, buf + j*2048 + tid*8);
  };

  const f32x4 fz = {0.f, 0.f, 0.f, 0.f};
  f32x4 acc[4][4];
#pragma unroll
  for (int a = 0; a < 4; ++a)
#pragma unroll
    for (int b = 0; b < 4; ++b) acc[a][b] = fz;

  stageA(As, 0);
  stage32(w1p, DIM, 0, Bs, tid);
  __syncthreads();
  int buf = 0;
  for (int kk = 0; kk < DIM/32; ++kk) {
    if (kk + 1 < DIM/32) {
      stageA(As + (buf ^ 1)*4096, (kk + 1)*32);
      stage32(w1p, DIM, (kk + 1)*32, Bs + (buf ^ 1)*4096, tid);
    }
    mfma_step32(As + buf*4096, Bs + buf*4096, acc, r16, g4, wm, wn);
    __syncthreads();
    buf ^= 1;
  }

  float b1v[4];
#pragma unroll
  for (int nf = 0; nf < 4; ++nf)
    b1v[nf] = b1[(size_t)e*FF + n*128 + wn*64 + nf*16 + r16];

  // epilogue: bias + gelu (rcp sigmoid), bounce via [128][136] LDS overlay
  unsigned short* hs = lds;
#pragma unroll
  for (int mf = 0; mf < 4; ++mf)
#pragma unroll
    for (int nf = 0; nf < 4; ++nf) {
      int col = wn*64 + nf*16 + r16;
#pragma unroll
      for (int i = 0; i < 4; ++i) {
        int row = wm*64 + mf*16 + g4*4 + i;
        float v = acc[mf][nf][i] + b1v[nf];
        float u = v * (0.7978845608028654f + 0.0356774081f*v*v);
        float gl = v * __builtin_amdgcn_rcpf(1.f + __expf(-2.f*u));  // v*sigmoid(2u)
        hs[row*136 + col] = (unsigned short)f2bf(gl);
      }
    }
  __syncthreads();
  unsigned short* hdst = h + (size_t)lt*(128*FF);
#pragma unroll
  for (int j = 0; j < 8; ++j) {
    int o = j*256 + tid;
    int row = o >> 4, part = o & 15;
    if (row0 + row < count)
      *(uint4*)(hdst + (size_t)row*FF + n*128 + part*8) =
          *(const uint4*)(hs + row*136 + part*8);
  }
}

// ---------------- K2 (chunked): out += w * (h_local[lt] @ W2^T + b2)
// bid = 32*(lt/8) + 8*n + (lt%8): 4 n-blocks of a tile share one XCD (W2 2MB L2-resident).
__global__ __launch_bounds__(256, 4) void k_gemm2(
    const unsigned short* __restrict__ h, const unsigned short* __restrict__ w2t,
    const float* __restrict__ b2, const int* __restrict__ tokl,
    const float* __restrict__ pwl, const int* __restrict__ cnt,
    float* __restrict__ out, int T0, int cap)
{
  const int bid = blockIdx.x;
  const int lt = (bid >> 5)*8 + (bid & 7);
  const int n  = (bid >> 3) & 3;
  const int gt = T0 + lt;
  if (lt >= cap || gt >= cnt[135]) return;
  const int e = tile_expert(cnt, gt);
  const int m = gt - cnt[e*16 + 3];
  const int count0 = cnt[e*16];
  const int count = count0 < HCAP ? count0 : HCAP;
  const int row0 = m*128;
  const int gbase = cnt[e*16 + 1];

  __shared__ __align__(16) unsigned short lds[16384];   // 32 KB
  unsigned short* As = lds;          // 2 x 4096 shorts
  unsigned short* Bs = lds + 8192;   // 2 x 4096 shorts

  const int tid = threadIdx.x, lane = tid & 63, wv = tid >> 6;
  const int r16 = lane & 15, g4 = lane >> 4;
  const int wm = wv >> 1, wn = wv & 1;

  const unsigned short* ap = h + (size_t)lt*(128*FF);
  const unsigned short* bp = w2t + (size_t)e*DIM*FF + (size_t)(n*128)*FF;

  const f32x4 fz = {0.f, 0.f, 0.f, 0.f};
  f32x4 acc[4][4];
#pragma unroll
  for (int a = 0; a < 4; ++a)
#pragma unroll
    for (int b = 0; b < 4; ++b) acc[a][b] = fz;

  stage32(ap, FF, 0, As, tid);
  stage32(bp, FF, 0, Bs, tid);
  __syncthreads();
  int buf = 0;
  for (int kk = 0; kk < FF/32; ++kk) {
    if (kk + 1 < FF/32) {
      stage32(ap, FF, (kk + 1)*32, As + (buf ^ 1)*4096, tid);
      stage32(bp, FF, (kk + 1)*32, Bs + (buf ^ 1)*4096, tid);
    }
    mfma_step32(As + buf*4096, Bs + buf*4096, acc, r16, g4, wm, wn);
    __syncthreads();
    buf ^= 1;
  }

  float b2v[4];
#pragma unroll
  for (int nf = 0; nf < 4; ++nf)
    b2v[nf] = b2[(size_t)e*DIM + n*128 + wn*64 + nf*16 + r16];

#pragma unroll
  for (int mf = 0; mf < 4; ++mf)
#pragma unroll
    for (int i = 0; i < 4; ++i) {
      int lrow = row0 + wm*64 + mf*16 + g4*4 + i;
      if (lrow < count) {
        int tk = tokl[gbase + lrow];
        float wg = pwl[gbase + lrow];
#pragma unroll
        for (int nf = 0; nf < 4; ++nf) {
          int d = n*128 + wn*64 + nf*16 + r16;
          atomicAdd(out + (size_t)tk*DIM + d, (acc[mf][nf][i] + b2v[nf]) * wg);
        }
      }
    }
}

extern "C" void kernel_launch(void* const* d_in, const int* in_sizes, int n_in,
                              void* d_out, int out_size, void* d_ws, size_t ws_size,
                              hipStream_t stream)
{
  const float* x  = (const float*)d_in[0];
  const float* Wr = (const float*)d_in[1];
  const float* W1 = (const float*)d_in[2];
  const float* b1 = (const float*)d_in[3];
  const float* W2 = (const float*)d_in[4];
  const float* b2 = (const float*)d_in[5];
  float* out = (float*)d_out;
  (void)in_sizes; (void)n_in;

  char* ws = (char*)d_ws;
  unsigned short* xb  = (unsigned short*)(ws);                    // 64 MB bf16 x (ungathered)
  unsigned short* w1t = (unsigned short*)(ws + 67108864);         // 16 MB W1^T bf16
  unsigned short* w2t = (unsigned short*)(ws + 83886080);         // 16 MB W2^T bf16
  int2*  tinfo = (int2*)(ws + 100663296);                         // 512 KB per-token routing
  int*   tokl  = (int*)(ws + 101187584);                          // 512 KB token list (gathered order)
  float* pwl   = (float*)(ws + 101711872);                        // 512 KB pair weights
  int*   cnt   = (int*)(ws + 102236160);                          // 1 KB counts/bases/tiles
  unsigned short* h = (unsigned short*)(ws + 102237184);          // chunk h, cap tiles

  const size_t FIXED = 102237184ULL;
  const size_t TILEB = (size_t)128 * FF * 2;
  long cap_l = (ws_size > FIXED) ? (long)((ws_size - FIXED) / TILEB) : 0;
  int cap = (int)(cap_l < MAXT ? cap_l : MAXT);
  if (cap > 256) cap = 256;     // keep h-chunk <= 134 MB
  if (cap < 8)  cap = 8;        // safety floor (ws >= 270 MB proven in r7)
  const int nch = (MAXT + cap - 1) / cap;
  const int ngrp = (cap + 7) / 8;

  hipMemsetAsync(cnt, 0, 256*sizeof(int), stream);
  hipMemsetAsync(d_out, 0, (size_t)out_size*sizeof(float), stream);

  dim3 g1(FF/32, DIM/32, NE);
  k_transpose_cast<<<g1, 256, 0, stream>>>(W1, w1t, DIM, FF);
  dim3 g2(DIM/32, FF/32, NE);
  k_transpose_cast<<<g2, 256, 0, stream>>>(W2, w2t, FF, DIM);

  k_router<<<N_TOK/64, 256, 0, stream>>>(x, Wr, xb, tinfo, cnt);
  k_offsets<<<1, 64, 0, stream>>>(cnt);
  k_fill<<<N_TOK/64, 128, 0, stream>>>(tinfo, tokl, pwl, cnt);

  for (int c = 0; c < nch; ++c) {
    const int T0 = c * cap;
    k_gemm1<<<ngrp*128, 256, 0, stream>>>(xb, w1t, b1, cnt, tokl, h, T0, cap);
    k_gemm2<<<ngrp*32,  256, 0, stream>>>(h, w2t, b2, tokl, pwl, cnt, out, T0, cap);
  }
}

// Round 16
// 1079.806 us; speedup vs baseline: 1.2052x; 1.0079x over previous
//
#include <hip/hip_runtime.h>
#include <cstdint>
#include <cstddef>

#define N_TOK 65536
#define DIM 512
#define FF 2048
#define NE 8
#define HCAP 24576           // per-expert row capacity covered by tile enumeration
#define MAXT 1032            // tight bound: sum_e ceil(count_e/128) <= 1031

typedef __attribute__((ext_vector_type(8))) short short8;
typedef __attribute__((ext_vector_type(4))) float f32x4;

__device__ __forceinline__ unsigned f2bf(float f) {
  unsigned u = __builtin_bit_cast(unsigned, f);
  u = u + 0x7fffu + ((u >> 16) & 1u);
  return (u >> 16) & 0xffffu;
}

__device__ __forceinline__ void gload_lds16(const void* g, void* l) {
  __builtin_amdgcn_global_load_lds((const __attribute__((address_space(1))) void*)g,
                                   (__attribute__((address_space(3))) void*)l, 16, 0, 0);
}

// ---------------- transpose + cast: in (rows x cols) f32 -> out (cols x rows) bf16, per expert
__global__ __launch_bounds__(256) void k_transpose_cast(
    const float* __restrict__ in, unsigned short* __restrict__ outp, int rows, int cols)
{
  __shared__ float tile[32][33];
  const float* ine = in + (size_t)blockIdx.z * rows * cols;
  unsigned short* oute = outp + (size_t)blockIdx.z * rows * cols;
  int tx = threadIdx.x & 31, ty = threadIdx.x >> 5;
  int r0 = blockIdx.y * 32, c0 = blockIdx.x * 32;
#pragma unroll
  for (int i = 0; i < 4; ++i)
    tile[ty + i*8][tx] = ine[(size_t)(r0 + ty + i*8)*cols + c0 + tx];
  __syncthreads();
#pragma unroll
  for (int i = 0; i < 4; ++i) {
    int r = c0 + ty + i*8, c = r0 + tx;
    oute[(size_t)r*rows + c] = (unsigned short)f2bf(tile[tx][ty + i*8]);
  }
}

// ---------------- router: logits, top-2, weight, counts; also casts x -> xb (bf16)
__global__ __launch_bounds__(256) void k_router(
    const float* __restrict__ x, const float* __restrict__ Wr,
    unsigned short* __restrict__ xb, int2* __restrict__ tinfo, int* __restrict__ cnt)
{
  __shared__ int lcnt[8];
  int tid = threadIdx.x, lane = tid & 63, wv = tid >> 6;
  if (tid < 8) lcnt[tid] = 0;
  float wr[8][8];
#pragma unroll
  for (int j = 0; j < 8; ++j) {
    const float4* p = (const float4*)(Wr + (size_t)(lane*8 + j)*NE);
    float4 a = p[0], b = p[1];
    wr[j][0]=a.x; wr[j][1]=a.y; wr[j][2]=a.z; wr[j][3]=a.w;
    wr[j][4]=b.x; wr[j][5]=b.y; wr[j][6]=b.z; wr[j][7]=b.w;
  }
  __syncthreads();
  int t0 = blockIdx.x*64 + wv*16;
  for (int it = 0; it < 16; ++it) {
    int t = t0 + it;
    const float4* xp = (const float4*)(x + (size_t)t*DIM + lane*8);
    float4 v0 = xp[0], v1 = xp[1];
    float xv[8] = {v0.x,v0.y,v0.z,v0.w,v1.x,v1.y,v1.z,v1.w};
    uint4 pk;
    pk.x = f2bf(xv[0]) | (f2bf(xv[1]) << 16);
    pk.y = f2bf(xv[2]) | (f2bf(xv[3]) << 16);
    pk.z = f2bf(xv[4]) | (f2bf(xv[5]) << 16);
    pk.w = f2bf(xv[6]) | (f2bf(xv[7]) << 16);
    *(uint4*)(xb + (size_t)t*DIM + lane*8) = pk;
    float lg[8];
#pragma unroll
    for (int e2 = 0; e2 < 8; ++e2) lg[e2] = 0.f;
#pragma unroll
    for (int j = 0; j < 8; ++j)
#pragma unroll
      for (int e2 = 0; e2 < 8; ++e2) lg[e2] += xv[j]*wr[j][e2];
#pragma unroll
    for (int off = 32; off >= 1; off >>= 1)
#pragma unroll
      for (int e2 = 0; e2 < 8; ++e2) lg[e2] += __shfl_xor(lg[e2], off, 64);
    int e0 = 0; float v0m = lg[0];
#pragma unroll
    for (int e2 = 1; e2 < 8; ++e2) if (lg[e2] > v0m) { v0m = lg[e2]; e0 = e2; }
    int e1 = -1; float v1m = -3.0e38f;
#pragma unroll
    for (int e2 = 0; e2 < 8; ++e2) if (e2 != e0 && lg[e2] > v1m) { v1m = lg[e2]; e1 = e2; }
    float w0 = 1.f / (1.f + __expf((v1m - v0m) * 0.4f));   // 1/T = 1/2.5
    if (lane == 0) {
      atomicAdd(&lcnt[e0], 1);
      atomicAdd(&lcnt[e1], 1);
      tinfo[t] = make_int2(e0 | (e1 << 8), __float_as_int(w0));
    }
  }
  __syncthreads();
  if (tid < 8) atomicAdd(&cnt[tid*16], lcnt[tid]);
}

// ---------------- pass 2: scan counts -> row bases, tile bases, total tiles; zero cursors
__global__ void k_offsets(int* cnt) {
  if (threadIdx.x == 0) {
    int base = 0, tb = 0;
    for (int e2 = 0; e2 < 8; ++e2) {
      int c = cnt[e2*16]; if (c > HCAP) c = HCAP;
      cnt[e2*16 + 1] = base;          // row base (gbase)
      base += cnt[e2*16];
      cnt[e2*16 + 2] = 0;             // fill cursor
      cnt[e2*16 + 3] = tb;            // tile base
      tb += (c + 127) >> 7;
    }
    cnt[135] = tb;                    // total tiles
  }
}

// ---------------- pass 3: slot assignment only (token list + weights; no x copy)
__global__ __launch_bounds__(128) void k_fill(
    const int2* __restrict__ tinfo, int* __restrict__ tokl,
    float* __restrict__ pwl, int* __restrict__ cnt)
{
  __shared__ int lc[8], lbase[8], gb[8];
  __shared__ unsigned char ce[128];
  __shared__ int csl[128];
  __shared__ float cw[128];
  int tid = threadIdx.x;
  if (tid < 8) { lc[tid] = 0; gb[tid] = cnt[tid*16 + 1]; }
  __syncthreads();
  if (tid < 64) {
    int t = blockIdx.x*64 + tid;
    int2 inf = tinfo[t];
    int e0 = inf.x & 0xff, e1 = (inf.x >> 8) & 0xff;
    float w0 = __int_as_float(inf.y);
    int i0 = tid*2, i1 = i0 + 1;
    ce[i0] = (unsigned char)e0; cw[i0] = w0;        csl[i0] = atomicAdd(&lc[e0], 1);
    ce[i1] = (unsigned char)e1; cw[i1] = 1.f - w0;  csl[i1] = atomicAdd(&lc[e1], 1);
  }
  __syncthreads();
  if (tid < 8) lbase[tid] = atomicAdd(&cnt[tid*16 + 2], lc[tid]);
  __syncthreads();
  int e = ce[tid];
  int p = gb[e] + lbase[e] + csl[tid];
  tokl[p] = blockIdx.x*64 + (tid >> 1);
  pwl[p]  = cw[tid];
}

// ================= 128x128 GEMM pieces — BK=32 double-buffered, 4 blocks/CU =================
// Bank-conflict-free swizzle for 64-B rows: slot XOR uses (row>>1)&3 so
// bank_start = (row&1)*16 + slot*4 walks 8 distinct (parity,slot) combos x 2 rows = 2-way (free).
// Write side: lrow = j*64 + (tid>>2) -> (lrow>>1)&3 = (tid>>3)&3.
__device__ __forceinline__ void stage32(
    const unsigned short* __restrict__ src, size_t stride, int k0,
    unsigned short* __restrict__ buf, int tid)
{
#pragma unroll
  for (int j = 0; j < 2; ++j) {
    int lrow = j*64 + (tid >> 2);
    gload_lds16(src + (size_t)lrow*stride + k0 + ((((tid & 3) ^ ((tid >> 3) & 3))) << 3),
                buf + j*2048 + tid*8);
  }
}

__device__ __forceinline__ int tile_expert(const int* cnt, int gt) {
  int e = 0;
#pragma unroll
  for (int k = 1; k < 8; ++k) if (gt >= cnt[k*16 + 3]) e = k;
  return e;
}

__device__ __forceinline__ void mfma_step32(
    const unsigned short* __restrict__ ab, const unsigned short* __restrict__ bb,
    f32x4 acc[4][4], int r16, int g4, int wm, int wn)
{
  short8 af[4], bf[4];
#pragma unroll
  for (int mf = 0; mf < 4; ++mf) {
    int row = wm*64 + mf*16 + r16;
    af[mf] = *(const short8*)(ab + row*32 + ((g4 ^ ((row >> 1) & 3)) << 3));
  }
#pragma unroll
  for (int nf = 0; nf < 4; ++nf) {
    int row = wn*64 + nf*16 + r16;
    bf[nf] = *(const short8*)(bb + row*32 + ((g4 ^ ((row >> 1) & 3)) << 3));
  }
  __builtin_amdgcn_s_setprio(1);
#pragma unroll
  for (int mf = 0; mf < 4; ++mf)
#pragma unroll
    for (int nf = 0; nf < 4; ++nf)
      acc[mf][nf] = __builtin_amdgcn_mfma_f32_16x16x32_bf16(
          af[mf], bf[nf], acc[mf][nf], 0, 0, 0);
  __builtin_amdgcn_s_setprio(0);
}

// ---------------- K1 (chunked): h_local[lt] = gelu(gather(xb) @ W1^T + b1)
// bid decode: n = (bid&7)|(((bid>>3)&1)<<3), lt = bid>>4  -> XCD = n%8 (W1 panels L2-resident).
__global__ __launch_bounds__(256, 4) void k_gemm1(
    const unsigned short* __restrict__ xb, const unsigned short* __restrict__ w1t,
    const float* __restrict__ b1, const int* __restrict__ cnt,
    const int* __restrict__ tokl, unsigned short* __restrict__ h, int T0, int cap)
{
  const int bid = blockIdx.x;
  const int n  = (bid & 7) | (((bid >> 3) & 1) << 3);
  const int lt = bid >> 4;
  const int gt = T0 + lt;
  if (lt >= cap || gt >= cnt[135]) return;
  const int e = tile_expert(cnt, gt);
  const int m = gt - cnt[e*16 + 3];
  const int count0 = cnt[e*16];
  const int count = count0 < HCAP ? count0 : HCAP;
  const int row0 = m*128;
  const int gbase = cnt[e*16 + 1];

  __shared__ __align__(16) unsigned short lds[17408];   // 34.8 KB (max of 32 KB bufs / hs)
  unsigned short* As = lds;          // 2 x 4096 shorts
  unsigned short* Bs = lds + 8192;   // 2 x 4096 shorts

  const int tid = threadIdx.x, lane = tid & 63, wv = tid >> 6;
  const int r16 = lane & 15, g4 = lane >> 4;
  const int wm = wv >> 1, wn = wv & 1;

  // gathered row bases: 2 per thread (rows tid>>2 and 64+(tid>>2)), clamped
  int rows2[2];
#pragma unroll
  for (int j = 0; j < 2; ++j) {
    int rr = row0 + j*64 + (tid >> 2);
    if (rr > count - 1) rr = count - 1;
    rows2[j] = tokl[gbase + rr];
  }
  const int axor = (((tid & 3) ^ ((tid >> 3) & 3))) << 3;
  const unsigned short* w1p = w1t + (size_t)e*FF*DIM + (size_t)(n*128)*DIM;

  auto stageA = [&](unsigned short* buf, int k0) {
#pragma unroll
    for (int j = 0; j < 2; ++j)
      gload_lds16(xb + (size_t)rows2[j]*DIM + k0 + axor, buf + j*2048 + tid*8);
  };

  const f32x4 fz = {0.f, 0.f, 0.f, 0.f};
  f32x4 acc[4][4];
#pragma unroll
  for (int a = 0; a < 4; ++a)
#pragma unroll
    for (int b = 0; b < 4; ++b) acc[a][b] = fz;

  stageA(As, 0);
  stage32(w1p, DIM, 0, Bs, tid);
  __syncthreads();
  int buf = 0;
  for (int kk = 0; kk < DIM/32; ++kk) {
    if (kk + 1 < DIM/32) {
      stageA(As + (buf ^ 1)*4096, (kk + 1)*32);
      stage32(w1p, DIM, (kk + 1)*32, Bs + (buf ^ 1)*4096, tid);
    }
    mfma_step32(As + buf*4096, Bs + buf*4096, acc, r16, g4, wm, wn);
    __syncthreads();
    buf ^= 1;
  }

  float b1v[4];
#pragma unroll
  for (int nf = 0; nf < 4; ++nf)
    b1v[nf] = b1[(size_t)e*FF + n*128 + wn*64 + nf*16 + r16];

  // epilogue: bias + gelu (rcp sigmoid), bounce via [128][136] LDS overlay
  unsigned short* hs = lds;
#pragma unroll
  for (int mf = 0; mf < 4; ++mf)
#pragma unroll
    for (int nf = 0; nf < 4; ++nf) {
      int col = wn*64 + nf*16 + r16;
#pragma unroll
      for (int i = 0; i < 4; ++i) {
        int row = wm*64 + mf*16 + g4*4 + i;
        float v = acc[mf][nf][i] + b1v[nf];
        float u = v * (0.7978845608028654f + 0.0356774081f*v*v);
        float gl = v * __builtin_amdgcn_rcpf(1.f + __expf(-2.f*u));  // v*sigmoid(2u)
        hs[row*136 + col] = (unsigned short)f2bf(gl);
      }
    }
  __syncthreads();
  unsigned short* hdst = h + (size_t)lt*(128*FF);
#pragma unroll
  for (int j = 0; j < 8; ++j) {
    int o = j*256 + tid;
    int row = o >> 4, part = o & 15;
    if (row0 + row < count)
      *(uint4*)(hdst + (size_t)row*FF + n*128 + part*8) =
          *(const uint4*)(hs + row*136 + part*8);
  }
}

// ---------------- K2 (chunked): out += w * (h_local[lt] @ W2^T + b2)
// bid = 32*(lt/8) + 8*n + (lt%8): 4 n-blocks of a tile share one XCD (W2 2MB L2-resident).
__global__ __launch_bounds__(256, 4) void k_gemm2(
    const unsigned short* __restrict__ h, const unsigned short* __restrict__ w2t,
    const float* __restrict__ b2, const int* __restrict__ tokl,
    const float* __restrict__ pwl, const int* __restrict__ cnt,
    float* __restrict__ out, int T0, int cap)
{
  const int bid = blockIdx.x;
  const int lt = (bid >> 5)*8 + (bid & 7);
  const int n  = (bid >> 3) & 3;
  const int gt = T0 + lt;
  if (lt >= cap || gt >= cnt[135]) return;
  const int e = tile_expert(cnt, gt);
  const int m = gt - cnt[e*16 + 3];
  const int count0 = cnt[e*16];
  const int count = count0 < HCAP ? count0 : HCAP;
  const int row0 = m*128;
  const int gbase = cnt[e*16 + 1];

  __shared__ __align__(16) unsigned short lds[16384];   // 32 KB
  unsigned short* As = lds;          // 2 x 4096 shorts
  unsigned short* Bs = lds + 8192;   // 2 x 4096 shorts

  const int tid = threadIdx.x, lane = tid & 63, wv = tid >> 6;
  const int r16 = lane & 15, g4 = lane >> 4;
  const int wm = wv >> 1, wn = wv & 1;

  const unsigned short* ap = h + (size_t)lt*(128*FF);
  const unsigned short* bp = w2t + (size_t)e*DIM*FF + (size_t)(n*128)*FF;

  const f32x4 fz = {0.f, 0.f, 0.f, 0.f};
  f32x4 acc[4][4];
#pragma unroll
  for (int a = 0; a < 4; ++a)
#pragma unroll
    for (int b = 0; b < 4; ++b) acc[a][b] = fz;

  stage32(ap, FF, 0, As, tid);
  stage32(bp, FF, 0, Bs, tid);
  __syncthreads();
  int buf = 0;
  for (int kk = 0; kk < FF/32; ++kk) {
    if (kk + 1 < FF/32) {
      stage32(ap, FF, (kk + 1)*32, As + (buf ^ 1)*4096, tid);
      stage32(bp, FF, (kk + 1)*32, Bs + (buf ^ 1)*4096, tid);
    }
    mfma_step32(As + buf*4096, Bs + buf*4096, acc, r16, g4, wm, wn);
    __syncthreads();
    buf ^= 1;
  }

  float b2v[4];
#pragma unroll
  for (int nf = 0; nf < 4; ++nf)
    b2v[nf] = b2[(size_t)e*DIM + n*128 + wn*64 + nf*16 + r16];

#pragma unroll
  for (int mf = 0; mf < 4; ++mf)
#pragma unroll
    for (int i = 0; i < 4; ++i) {
      int lrow = row0 + wm*64 + mf*16 + g4*4 + i;
      if (lrow < count) {
        int tk = tokl[gbase + lrow];
        float wg = pwl[gbase + lrow];
#pragma unroll
        for (int nf = 0; nf < 4; ++nf) {
          int d = n*128 + wn*64 + nf*16 + r16;
          atomicAdd(out + (size_t)tk*DIM + d, (acc[mf][nf][i] + b2v[nf]) * wg);
        }
      }
    }
}

extern "C" void kernel_launch(void* const* d_in, const int* in_sizes, int n_in,
                              void* d_out, int out_size, void* d_ws, size_t ws_size,
                              hipStream_t stream)
{
  const float* x  = (const float*)d_in[0];
  const float* Wr = (const float*)d_in[1];
  const float* W1 = (const float*)d_in[2];
  const float* b1 = (const float*)d_in[3];
  const float* W2 = (const float*)d_in[4];
  const float* b2 = (const float*)d_in[5];
  float* out = (float*)d_out;
  (void)in_sizes; (void)n_in;

  char* ws = (char*)d_ws;
  unsigned short* xb  = (unsigned short*)(ws);                    // 64 MB bf16 x (ungathered)
  unsigned short* w1t = (unsigned short*)(ws + 67108864);         // 16 MB W1^T bf16
  unsigned short* w2t = (unsigned short*)(ws + 83886080);         // 16 MB W2^T bf16
  int2*  tinfo = (int2*)(ws + 100663296);                         // 512 KB per-token routing
  int*   tokl  = (int*)(ws + 101187584);                          // 512 KB token list (gathered order)
  float* pwl   = (float*)(ws + 101711872);                        // 512 KB pair weights
  int*   cnt   = (int*)(ws + 102236160);                          // 1 KB counts/bases/tiles
  unsigned short* h = (unsigned short*)(ws + 102237184);          // chunk h, cap tiles

  const size_t FIXED = 102237184ULL;
  const size_t TILEB = (size_t)128 * FF * 2;
  long cap_l = (ws_size > FIXED) ? (long)((ws_size - FIXED) / TILEB) : 0;
  int cap = (int)(cap_l < MAXT ? cap_l : MAXT);
  if (cap > 256) cap = 256;     // keep h-chunk <= 134 MB
  if (cap < 8)  cap = 8;        // safety floor (ws >= 270 MB proven in r7)
  const int nch = (MAXT + cap - 1) / cap;
  const int ngrp = (cap + 7) / 8;

  hipMemsetAsync(cnt, 0, 256*sizeof(int), stream);
  hipMemsetAsync(d_out, 0, (size_t)out_size*sizeof(float), stream);

  dim3 g1(FF/32, DIM/32, NE);
  k_transpose_cast<<<g1, 256, 0, stream>>>(W1, w1t, DIM, FF);
  dim3 g2(DIM/32, FF/32, NE);
  k_transpose_cast<<<g2, 256, 0, stream>>>(W2, w2t, FF, DIM);

  k_router<<<N_TOK/64, 256, 0, stream>>>(x, Wr, xb, tinfo, cnt);
  k_offsets<<<1, 64, 0, stream>>>(cnt);
  k_fill<<<N_TOK/64, 128, 0, stream>>>(tinfo, tokl, pwl, cnt);

  for (int c = 0; c < nch; ++c) {
    const int T0 = c * cap;
    k_gemm1<<<ngrp*128, 256, 0, stream>>>(xb, w1t, b1, cnt, tokl, h, T0, cap);
    k_gemm2<<<ngrp*32,  256, 0, stream>>>(h, w2t, b2, tokl, pwl, cnt, out, T0, cap);
  }
}

// Round 17
// 1023.377 us; speedup vs baseline: 1.2716x; 1.0551x over previous
//
#include <hip/hip_runtime.h>
#include <cstdint>
#include <cstddef>

#define N_TOK 65536
#define DIM 512
#define FF 2048
#define NE 8
#define HCAP 24576           // per-expert row capacity covered by tile enumeration
#define MAXT 1032            // tight bound: sum_e ceil(count_e/128) <= 1031
#define CAPF 256             // fused-path chunk size (tiles)
#define HSLOTS 512           // fused-path double-region h: slot = gt % 512

typedef __attribute__((ext_vector_type(8))) short short8;
typedef __attribute__((ext_vector_type(4))) float f32x4;

__device__ __forceinline__ unsigned f2bf(float f) {
  unsigned u = __builtin_bit_cast(unsigned, f);
  u = u + 0x7fffu + ((u >> 16) & 1u);
  return (u >> 16) & 0xffffu;
}

__device__ __forceinline__ void gload_lds16(const void* g, void* l) {
  __builtin_amdgcn_global_load_lds((const __attribute__((address_space(1))) void*)g,
                                   (__attribute__((address_space(3))) void*)l, 16, 0, 0);
}

// ---------------- transpose + cast: in (rows x cols) f32 -> out (cols x rows) bf16, per expert
__global__ __launch_bounds__(256) void k_transpose_cast(
    const float* __restrict__ in, unsigned short* __restrict__ outp, int rows, int cols)
{
  __shared__ float tile[32][33];
  const float* ine = in + (size_t)blockIdx.z * rows * cols;
  unsigned short* oute = outp + (size_t)blockIdx.z * rows * cols;
  int tx = threadIdx.x & 31, ty = threadIdx.x >> 5;
  int r0 = blockIdx.y * 32, c0 = blockIdx.x * 32;
#pragma unroll
  for (int i = 0; i < 4; ++i)
    tile[ty + i*8][tx] = ine[(size_t)(r0 + ty + i*8)*cols + c0 + tx];
  __syncthreads();
#pragma unroll
  for (int i = 0; i < 4; ++i) {
    int r = c0 + ty + i*8, c = r0 + tx;
    oute[(size_t)r*rows + c] = (unsigned short)f2bf(tile[tx][ty + i*8]);
  }
}

// ---------------- router: logits, top-2, weight, counts; also casts x -> xb (bf16)
__global__ __launch_bounds__(256) void k_router(
    const float* __restrict__ x, const float* __restrict__ Wr,
    unsigned short* __restrict__ xb, int2* __restrict__ tinfo, int* __restrict__ cnt)
{
  __shared__ int lcnt[8];
  int tid = threadIdx.x, lane = tid & 63, wv = tid >> 6;
  if (tid < 8) lcnt[tid] = 0;
  float wr[8][8];
#pragma unroll
  for (int j = 0; j < 8; ++j) {
    const float4* p = (const float4*)(Wr + (size_t)(lane*8 + j)*NE);
    float4 a = p[0], b = p[1];
    wr[j][0]=a.x; wr[j][1]=a.y; wr[j][2]=a.z; wr[j][3]=a.w;
    wr[j][4]=b.x; wr[j][5]=b.y; wr[j][6]=b.z; wr[j][7]=b.w;
  }
  __syncthreads();
  int t0 = blockIdx.x*64 + wv*16;
  for (int it = 0; it < 16; ++it) {
    int t = t0 + it;
    const float4* xp = (const float4*)(x + (size_t)t*DIM + lane*8);
    float4 v0 = xp[0], v1 = xp[1];
    float xv[8] = {v0.x,v0.y,v0.z,v0.w,v1.x,v1.y,v1.z,v1.w};
    uint4 pk;
    pk.x = f2bf(xv[0]) | (f2bf(xv[1]) << 16);
    pk.y = f2bf(xv[2]) | (f2bf(xv[3]) << 16);
    pk.z = f2bf(xv[4]) | (f2bf(xv[5]) << 16);
    pk.w = f2bf(xv[6]) | (f2bf(xv[7]) << 16);
    *(uint4*)(xb + (size_t)t*DIM + lane*8) = pk;
    float lg[8];
#pragma unroll
    for (int e2 = 0; e2 < 8; ++e2) lg[e2] = 0.f;
#pragma unroll
    for (int j = 0; j < 8; ++j)
#pragma unroll
      for (int e2 = 0; e2 < 8; ++e2) lg[e2] += xv[j]*wr[j][e2];
#pragma unroll
    for (int off = 32; off >= 1; off >>= 1)
#pragma unroll
      for (int e2 = 0; e2 < 8; ++e2) lg[e2] += __shfl_xor(lg[e2], off, 64);
    int e0 = 0; float v0m = lg[0];
#pragma unroll
    for (int e2 = 1; e2 < 8; ++e2) if (lg[e2] > v0m) { v0m = lg[e2]; e0 = e2; }
    int e1 = -1; float v1m = -3.0e38f;
#pragma unroll
    for (int e2 = 0; e2 < 8; ++e2) if (e2 != e0 && lg[e2] > v1m) { v1m = lg[e2]; e1 = e2; }
    float w0 = 1.f / (1.f + __expf((v1m - v0m) * 0.4f));   // 1/T = 1/2.5
    if (lane == 0) {
      atomicAdd(&lcnt[e0], 1);
      atomicAdd(&lcnt[e1], 1);
      tinfo[t] = make_int2(e0 | (e1 << 8), __float_as_int(w0));
    }
  }
  __syncthreads();
  if (tid < 8) atomicAdd(&cnt[tid*16], lcnt[tid]);
}

// ---------------- pass 2: scan counts -> row bases, tile bases, total tiles; zero cursors
__global__ void k_offsets(int* cnt) {
  if (threadIdx.x == 0) {
    int base = 0, tb = 0;
    for (int e2 = 0; e2 < 8; ++e2) {
      int c = cnt[e2*16]; if (c > HCAP) c = HCAP;
      cnt[e2*16 + 1] = base;          // row base (gbase)
      base += cnt[e2*16];
      cnt[e2*16 + 2] = 0;             // fill cursor
      cnt[e2*16 + 3] = tb;            // tile base
      tb += (c + 127) >> 7;
    }
    cnt[135] = tb;                    // total tiles
  }
}

// ---------------- pass 3: slot assignment only (token list + weights; no x copy)
__global__ __launch_bounds__(128) void k_fill(
    const int2* __restrict__ tinfo, int* __restrict__ tokl,
    float* __restrict__ pwl, int* __restrict__ cnt)
{
  __shared__ int lc[8], lbase[8], gb[8];
  __shared__ unsigned char ce[128];
  __shared__ int csl[128];
  __shared__ float cw[128];
  int tid = threadIdx.x;
  if (tid < 8) { lc[tid] = 0; gb[tid] = cnt[tid*16 + 1]; }
  __syncthreads();
  if (tid < 64) {
    int t = blockIdx.x*64 + tid;
    int2 inf = tinfo[t];
    int e0 = inf.x & 0xff, e1 = (inf.x >> 8) & 0xff;
    float w0 = __int_as_float(inf.y);
    int i0 = tid*2, i1 = i0 + 1;
    ce[i0] = (unsigned char)e0; cw[i0] = w0;        csl[i0] = atomicAdd(&lc[e0], 1);
    ce[i1] = (unsigned char)e1; cw[i1] = 1.f - w0;  csl[i1] = atomicAdd(&lc[e1], 1);
  }
  __syncthreads();
  if (tid < 8) lbase[tid] = atomicAdd(&cnt[tid*16 + 2], lc[tid]);
  __syncthreads();
  int e = ce[tid];
  int p = gb[e] + lbase[e] + csl[tid];
  tokl[p] = blockIdx.x*64 + (tid >> 1);
  pwl[p]  = cw[tid];
}

// ================= 128x128 GEMM pieces — BK=32 double-buffered, 4 blocks/CU =================
// Conflict-free swizzle (r16): slot XOR uses (row>>1)&3 -> 2-way banked (free).
__device__ __forceinline__ void stage32(
    const unsigned short* __restrict__ src, size_t stride, int k0,
    unsigned short* __restrict__ buf, int tid)
{
#pragma unroll
  for (int j = 0; j < 2; ++j) {
    int lrow = j*64 + (tid >> 2);
    gload_lds16(src + (size_t)lrow*stride + k0 + ((((tid & 3) ^ ((tid >> 3) & 3))) << 3),
                buf + j*2048 + tid*8);
  }
}

__device__ __forceinline__ int tile_expert(const int* cnt, int gt) {
  int e = 0;
#pragma unroll
  for (int k = 1; k < 8; ++k) if (gt >= cnt[k*16 + 3]) e = k;
  return e;
}

__device__ __forceinline__ void mfma_step32(
    const unsigned short* __restrict__ ab, const unsigned short* __restrict__ bb,
    f32x4 acc[4][4], int r16, int g4, int wm, int wn)
{
  short8 af[4], bf[4];
#pragma unroll
  for (int mf = 0; mf < 4; ++mf) {
    int row = wm*64 + mf*16 + r16;
    af[mf] = *(const short8*)(ab + row*32 + ((g4 ^ ((row >> 1) & 3)) << 3));
  }
#pragma unroll
  for (int nf = 0; nf < 4; ++nf) {
    int row = wn*64 + nf*16 + r16;
    bf[nf] = *(const short8*)(bb + row*32 + ((g4 ^ ((row >> 1) & 3)) << 3));
  }
  __builtin_amdgcn_s_setprio(1);
#pragma unroll
  for (int mf = 0; mf < 4; ++mf)
#pragma unroll
    for (int nf = 0; nf < 4; ++nf)
      acc[mf][nf] = __builtin_amdgcn_mfma_f32_16x16x32_bf16(
          af[mf], bf[nf], acc[mf][nf], 0, 0, 0);
  __builtin_amdgcn_s_setprio(0);
}

// ---- K1 body: h[slot] = gelu(gather(xb) @ W1^T + b1); slot chosen by caller
__device__ __forceinline__ void gemm1_body(
    const unsigned short* __restrict__ xb, const unsigned short* __restrict__ w1t,
    const float* __restrict__ b1, const int* __restrict__ cnt,
    const int* __restrict__ tokl, unsigned short* __restrict__ hdst,
    int gt, int n, unsigned short* lds, int tid)
{
  const int e = tile_expert(cnt, gt);
  const int m = gt - cnt[e*16 + 3];
  const int count0 = cnt[e*16];
  const int count = count0 < HCAP ? count0 : HCAP;
  const int row0 = m*128;
  const int gbase = cnt[e*16 + 1];

  unsigned short* As = lds;
  unsigned short* Bs = lds + 8192;
  const int lane = tid & 63, wv = tid >> 6;
  const int r16 = lane & 15, g4 = lane >> 4;
  const int wm = wv >> 1, wn = wv & 1;

  int rows2[2];
#pragma unroll
  for (int j = 0; j < 2; ++j) {
    int rr = row0 + j*64 + (tid >> 2);
    if (rr > count - 1) rr = count - 1;
    rows2[j] = tokl[gbase + rr];
  }
  const int axor = (((tid & 3) ^ ((tid >> 3) & 3))) << 3;
  const unsigned short* w1p = w1t + (size_t)e*FF*DIM + (size_t)(n*128)*DIM;

  const f32x4 fz = {0.f, 0.f, 0.f, 0.f};
  f32x4 acc[4][4];
#pragma unroll
  for (int a = 0; a < 4; ++a)
#pragma unroll
    for (int b = 0; b < 4; ++b) acc[a][b] = fz;

#pragma unroll
  for (int j = 0; j < 2; ++j)
    gload_lds16(xb + (size_t)rows2[j]*DIM + axor, As + j*2048 + tid*8);
  stage32(w1p, DIM, 0, Bs, tid);
  __syncthreads();
  int buf = 0;
  for (int kk = 0; kk < DIM/32; ++kk) {
    if (kk + 1 < DIM/32) {
#pragma unroll
      for (int j = 0; j < 2; ++j)
        gload_lds16(xb + (size_t)rows2[j]*DIM + (kk + 1)*32 + axor,
                    As + (buf ^ 1)*4096 + j*2048 + tid*8);
      stage32(w1p, DIM, (kk + 1)*32, Bs + (buf ^ 1)*4096, tid);
    }
    mfma_step32(As + buf*4096, Bs + buf*4096, acc, r16, g4, wm, wn);
    __syncthreads();
    buf ^= 1;
  }

  float b1v[4];
#pragma unroll
  for (int nf = 0; nf < 4; ++nf)
    b1v[nf] = b1[(size_t)e*FF + n*128 + wn*64 + nf*16 + r16];

  unsigned short* hs = lds;
#pragma unroll
  for (int mf = 0; mf < 4; ++mf)
#pragma unroll
    for (int nf = 0; nf < 4; ++nf) {
      int col = wn*64 + nf*16 + r16;
#pragma unroll
      for (int i = 0; i < 4; ++i) {
        int row = wm*64 + mf*16 + g4*4 + i;
        float v = acc[mf][nf][i] + b1v[nf];
        float u = v * (0.7978845608028654f + 0.0356774081f*v*v);
        float gl = v * __builtin_amdgcn_rcpf(1.f + __expf(-2.f*u));  // v*sigmoid(2u)
        hs[row*136 + col] = (unsigned short)f2bf(gl);
      }
    }
  __syncthreads();
#pragma unroll
  for (int j = 0; j < 8; ++j) {
    int o = j*256 + tid;
    int row = o >> 4, part = o & 15;
    if (row0 + row < count)
      *(uint4*)(hdst + (size_t)row*FF + n*128 + part*8) =
          *(const uint4*)(hs + row*136 + part*8);
  }
}

// ---- K2 body: out += w * (h_tile @ W2^T + b2); h tile pointer chosen by caller
__device__ __forceinline__ void gemm2_body(
    const unsigned short* __restrict__ ap, const unsigned short* __restrict__ w2t,
    const float* __restrict__ b2, const int* __restrict__ tokl,
    const float* __restrict__ pwl, const int* __restrict__ cnt,
    float* __restrict__ out, int gt, int n, unsigned short* lds, int tid)
{
  const int e = tile_expert(cnt, gt);
  const int m = gt - cnt[e*16 + 3];
  const int count0 = cnt[e*16];
  const int count = count0 < HCAP ? count0 : HCAP;
  const int row0 = m*128;
  const int gbase = cnt[e*16 + 1];

  unsigned short* As = lds;
  unsigned short* Bs = lds + 8192;
  const int lane = tid & 63, wv = tid >> 6;
  const int r16 = lane & 15, g4 = lane >> 4;
  const int wm = wv >> 1, wn = wv & 1;

  const unsigned short* bp = w2t + (size_t)e*DIM*FF + (size_t)(n*128)*FF;

  const f32x4 fz = {0.f, 0.f, 0.f, 0.f};
  f32x4 acc[4][4];
#pragma unroll
  for (int a = 0; a < 4; ++a)
#pragma unroll
    for (int b = 0; b < 4; ++b) acc[a][b] = fz;

  stage32(ap, FF, 0, As, tid);
  stage32(bp, FF, 0, Bs, tid);
  __syncthreads();
  int buf = 0;
  for (int kk = 0; kk < FF/32; ++kk) {
    if (kk + 1 < FF/32) {
      stage32(ap, FF, (kk + 1)*32, As + (buf ^ 1)*4096, tid);
      stage32(bp, FF, (kk + 1)*32, Bs + (buf ^ 1)*4096, tid);
    }
    mfma_step32(As + buf*4096, Bs + buf*4096, acc, r16, g4, wm, wn);
    __syncthreads();
    buf ^= 1;
  }

  float b2v[4];
#pragma unroll
  for (int nf = 0; nf < 4; ++nf)
    b2v[nf] = b2[(size_t)e*DIM + n*128 + wn*64 + nf*16 + r16];

#pragma unroll
  for (int mf = 0; mf < 4; ++mf)
#pragma unroll
    for (int i = 0; i < 4; ++i) {
      int lrow = row0 + wm*64 + mf*16 + g4*4 + i;
      if (lrow < count) {
        int tk = tokl[gbase + lrow];
        float wg = pwl[gbase + lrow];
#pragma unroll
        for (int nf = 0; nf < 4; ++nf) {
          int d = n*128 + wn*64 + nf*16 + r16;
          atomicAdd(out + (size_t)tk*DIM + d, (acc[mf][nf][i] + b2v[nf]) * wg);
        }
      }
    }
}

// ---------------- serial-path kernels (r16, via shared bodies; h chunk-local) ----------------
__global__ __launch_bounds__(256, 4) void k_gemm1(
    const unsigned short* __restrict__ xb, const unsigned short* __restrict__ w1t,
    const float* __restrict__ b1, const int* __restrict__ cnt,
    const int* __restrict__ tokl, unsigned short* __restrict__ h, int T0, int cap)
{
  __shared__ __align__(16) unsigned short lds[17408];
  const int bid = blockIdx.x;
  const int n  = (bid & 7) | (((bid >> 3) & 1) << 3);
  const int lt = bid >> 4;
  const int gt = T0 + lt;
  if (lt >= cap || gt >= cnt[135]) return;
  gemm1_body(xb, w1t, b1, cnt, tokl, h + (size_t)lt*(128*FF), gt, n, lds, threadIdx.x);
}

__global__ __launch_bounds__(256, 4) void k_gemm2(
    const unsigned short* __restrict__ h, const unsigned short* __restrict__ w2t,
    const float* __restrict__ b2, const int* __restrict__ tokl,
    const float* __restrict__ pwl, const int* __restrict__ cnt,
    float* __restrict__ out, int T0, int cap)
{
  __shared__ __align__(16) unsigned short lds[16384];
  const int bid = blockIdx.x;
  const int lt = (bid >> 5)*8 + (bid & 7);
  const int n  = (bid >> 3) & 3;
  const int gt = T0 + lt;
  if (lt >= cap || gt >= cnt[135]) return;
  gemm2_body(h + (size_t)lt*(128*FF), w2t, b2, tokl, pwl, cnt, out, gt, n, lds, threadIdx.x);
}

// ---------------- fused pipelined step (ws-gated): blocks [0,nb2) = K2(chunk c-1),
// blocks [nb2,nb2+nb1) = K1(chunk c). h slot = gt % 512; CAPF=256 chunks -> regions disjoint.
// K2 blocks at low bids start first (latency-bound), K1 throughput blocks fill behind.
__global__ __launch_bounds__(256, 4) void k_step(
    const unsigned short* __restrict__ xb, const unsigned short* __restrict__ w1t,
    const unsigned short* __restrict__ w2t, const float* __restrict__ b1,
    const float* __restrict__ b2, const int* __restrict__ tokl,
    const float* __restrict__ pwl, const int* __restrict__ cnt,
    unsigned short* __restrict__ h, float* __restrict__ out,
    int T0k2, int T0k1, int nb2)
{
  __shared__ __align__(16) unsigned short lds[17408];
  if ((int)blockIdx.x < nb2) {
    const int bid = blockIdx.x;
    const int lt = (bid >> 5)*8 + (bid & 7);
    const int n  = (bid >> 3) & 3;
    const int gt = T0k2 + lt;
    if (lt >= CAPF || gt >= cnt[135]) return;
    gemm2_body(h + (size_t)(gt & (HSLOTS - 1))*(128*FF), w2t, b2, tokl, pwl, cnt,
               out, gt, n, lds, threadIdx.x);
  } else {
    const int bid = blockIdx.x - nb2;
    const int n  = (bid & 7) | (((bid >> 3) & 1) << 3);
    const int lt = bid >> 4;
    const int gt = T0k1 + lt;
    if (lt >= CAPF || gt >= cnt[135]) return;
    gemm1_body(xb, w1t, b1, cnt, tokl, h + (size_t)(gt & (HSLOTS - 1))*(128*FF),
               gt, n, lds, threadIdx.x);
  }
}

extern "C" void kernel_launch(void* const* d_in, const int* in_sizes, int n_in,
                              void* d_out, int out_size, void* d_ws, size_t ws_size,
                              hipStream_t stream)
{
  const float* x  = (const float*)d_in[0];
  const float* Wr = (const float*)d_in[1];
  const float* W1 = (const float*)d_in[2];
  const float* b1 = (const float*)d_in[3];
  const float* W2 = (const float*)d_in[4];
  const float* b2 = (const float*)d_in[5];
  float* out = (float*)d_out;
  (void)in_sizes; (void)n_in;

  char* ws = (char*)d_ws;
  unsigned short* xb  = (unsigned short*)(ws);                    // 64 MB bf16 x (ungathered)
  unsigned short* w1t = (unsigned short*)(ws + 67108864);         // 16 MB W1^T bf16
  unsigned short* w2t = (unsigned short*)(ws + 83886080);         // 16 MB W2^T bf16
  int2*  tinfo = (int2*)(ws + 100663296);                         // 512 KB per-token routing
  int*   tokl  = (int*)(ws + 101187584);                          // 512 KB token list (gathered order)
  float* pwl   = (float*)(ws + 101711872);                        // 512 KB pair weights
  int*   cnt   = (int*)(ws + 102236160);                          // 1 KB counts/bases/tiles
  unsigned short* h = (unsigned short*)(ws + 102237184);          // h: 512 slots (fused) or chunk

  const size_t FIXED = 102237184ULL;
  const size_t TILEB = (size_t)128 * FF * 2;                      // 512 KB per h tile
  const int fused = (ws_size >= FIXED + (size_t)HSLOTS * TILEB);  // needs ~371 MB

  hipMemsetAsync(cnt, 0, 256*sizeof(int), stream);
  hipMemsetAsync(d_out, 0, (size_t)out_size*sizeof(float), stream);

  dim3 g1(FF/32, DIM/32, NE);
  k_transpose_cast<<<g1, 256, 0, stream>>>(W1, w1t, DIM, FF);
  dim3 g2(DIM/32, FF/32, NE);
  k_transpose_cast<<<g2, 256, 0, stream>>>(W2, w2t, FF, DIM);

  k_router<<<N_TOK/64, 256, 0, stream>>>(x, Wr, xb, tinfo, cnt);
  k_offsets<<<1, 64, 0, stream>>>(cnt);
  k_fill<<<N_TOK/64, 128, 0, stream>>>(tinfo, tokl, pwl, cnt);

  if (fused) {
    const int nch = (MAXT + CAPF - 1) / CAPF;                     // 5
    for (int c = 0; c <= nch; ++c) {
      const int nb2 = (c > 0)   ? CAPF*4  : 0;                    // 1024 K2 blocks
      const int nb1 = (c < nch) ? CAPF*16 : 0;                    // 4096 K1 blocks
      k_step<<<nb2 + nb1, 256, 0, stream>>>(xb, w1t, w2t, b1, b2, tokl, pwl, cnt,
                                            h, out, (c - 1)*CAPF, c*CAPF, nb2);
    }
  } else {
    long cap_l = (ws_size > FIXED) ? (long)((ws_size - FIXED) / TILEB) : 0;
    int cap = (int)(cap_l < MAXT ? cap_l : MAXT);
    if (cap > 256) cap = 256;
    if (cap < 8)  cap = 8;
    const int nch = (MAXT + cap - 1) / cap;
    const int ngrp = (cap + 7) / 8;
    for (int c = 0; c < nch; ++c) {
      const int T0 = c * cap;
      k_gemm1<<<ngrp*128, 256, 0, stream>>>(xb, w1t, b1, cnt, tokl, h, T0, cap);
      k_gemm2<<<ngrp*32,  256, 0, stream>>>(h, w2t, b2, tokl, pwl, cnt, out, T0, cap);
    }
  }
}